// Round 13
// baseline (216.239 us; speedup 1.0000x reference)
//
#include <hip/hip_runtime.h>
#include <cmath>

#define FEAT_DIM 1024
#define MM 32
#define KK 256
#define DD 32
#define BB 8192

constexpr float BN_EPS = 1e-5f;

typedef float f32x4 __attribute__((ext_vector_type(4)));

__device__ __forceinline__ float wave_fsum(float v) {
    #pragma unroll
    for (int s = 32; s >= 1; s >>= 1) v += __shfl_xor(v, s);
    return v;
}

// ---- DPP-based full-wave reductions: VALU-rate, result broadcast via SGPR ----
template <int CTRL, int RM = 0xf>
__device__ __forceinline__ float dppf(float v) {
    int r = __builtin_amdgcn_update_dpp(__builtin_bit_cast(int, v),
                                        __builtin_bit_cast(int, v),
                                        CTRL, RM, 0xf, false);
    return __builtin_bit_cast(float, r);
}
__device__ __forceinline__ float wave_dpp_max(float v) {
    v = fmaxf(v, dppf<0xB1>(v));
    v = fmaxf(v, dppf<0x4E>(v));
    v = fmaxf(v, dppf<0x141>(v));
    v = fmaxf(v, dppf<0x140>(v));
    v = fmaxf(v, dppf<0x142, 0xa>(v));
    v = fmaxf(v, dppf<0x143, 0xc>(v));
    return __builtin_bit_cast(float, __builtin_amdgcn_readlane(__builtin_bit_cast(int, v), 63));
}
__device__ __forceinline__ float wave_dpp_sum(float v) {
    v += dppf<0xB1>(v);
    v += dppf<0x4E>(v);
    v += dppf<0x141>(v);
    v += dppf<0x140>(v);
    v += dppf<0x142, 0xa>(v);
    v += dppf<0x143, 0xc>(v);
    return __builtin_bit_cast(float, __builtin_amdgcn_readlane(__builtin_bit_cast(int, v), 63));
}

// ---------- P0: L2-normalize x per (b,m); zero stats ----------
__global__ void k_norm(const float* __restrict__ x, float* __restrict__ xn,
                       double* __restrict__ stats) {
    if (blockIdx.x == 0 && threadIdx.x < 2 * MM) stats[threadIdx.x] = 0.0;
    const int t = blockIdx.x * blockDim.x + threadIdx.x;
    float4 v = ((const float4*)x)[t];
    float ss = v.x*v.x + v.y*v.y + v.z*v.z + v.w*v.w;
    #pragma unroll
    for (int s = 1; s < 8; s <<= 1) ss += __shfl_xor(ss, s);
    const float r = 1.0f / fmaxf(sqrtf(ss), 1e-12f);
    float4 o = {v.x*r, v.y*r, v.z*r, v.w*r};
    ((float4*)xn)[t] = o;
}

// ---------- P1a: per-m codebook sums S_m and Gram G_m = C^T C ----------
__global__ void k_gram(const float* __restrict__ Ck, float* __restrict__ G,
                       float* __restrict__ S) {
    __shared__ float CT[DD][KK + 4];
    const int m = blockIdx.x, part = blockIdx.y;
    const int t = threadIdx.x, wid = t >> 6, lane = t & 63;
    const float4* cp = (const float4*)(Ck + ((size_t)m * KK + t) * DD);
    #pragma unroll
    for (int i = 0; i < 8; ++i) {
        float4 v = cp[i];
        CT[4*i+0][t] = v.x; CT[4*i+1][t] = v.y;
        CT[4*i+2][t] = v.z; CT[4*i+3][t] = v.w;
    }
    __syncthreads();
    #pragma unroll 1
    for (int ei = 0; ei < 32; ++ei) {
        const int e = part * 128 + wid * 32 + ei;
        const int i = e >> 5, j = e & 31;
        float acc = 0.f;
        #pragma unroll
        for (int c4 = 0; c4 < 4; ++c4)
            acc = fmaf(CT[i][lane + 64*c4], CT[j][lane + 64*c4], acc);
        acc = wave_fsum(acc);
        if (lane == 0) G[((size_t)m * DD + i) * DD + j] = acc;
    }
    if (part == 0 && wid == 0) {
        #pragma unroll 1
        for (int d = 0; d < DD; ++d) {
            float a = 0.f;
            #pragma unroll
            for (int c4 = 0; c4 < 4; ++c4) a += CT[d][lane + 64*c4];
            a = wave_fsum(a);
            if (lane == 0) S[m * DD + d] = a;
        }
    }
}

// ---------- P1b: stats via quadratic form: sum = x.S, sumsq = x^T G x ----------
__global__ void k_stats2(const float* __restrict__ xn, const float* __restrict__ G,
                         const float* __restrict__ S, double* __restrict__ stats) {
    const int m = blockIdx.x;
    const int b = blockIdx.y * 256 + threadIdx.x;
    float xv[DD];
    {
        const float4* xp = (const float4*)(xn + (size_t)b * FEAT_DIM + m * DD);
        #pragma unroll
        for (int i = 0; i < 8; ++i) {
            float4 v = xp[i];
            xv[4*i+0]=v.x; xv[4*i+1]=v.y; xv[4*i+2]=v.z; xv[4*i+3]=v.w;
        }
    }
    const float4* Gp = (const float4*)(G + (size_t)m * DD * DD);
    const float*  Sp = S + m * DD;
    float q = 0.f, s = 0.f;
    #pragma unroll 4
    for (int i = 0; i < DD; ++i) {
        float y = 0.f;
        #pragma unroll
        for (int jv = 0; jv < 8; ++jv) {
            float4 g = Gp[i * 8 + jv];
            y = fmaf(g.x, xv[4*jv+0], y); y = fmaf(g.y, xv[4*jv+1], y);
            y = fmaf(g.z, xv[4*jv+2], y); y = fmaf(g.w, xv[4*jv+3], y);
        }
        q = fmaf(y, xv[i], q);
    }
    #pragma unroll
    for (int i = 0; i < DD; ++i) s = fmaf(Sp[i], xv[i], s);
    q = wave_fsum(q); s = wave_fsum(s);
    __shared__ float lq[4], ls[4];
    const int wid = threadIdx.x >> 6, lane = threadIdx.x & 63;
    if (lane == 0) { lq[wid] = q; ls[wid] = s; }
    __syncthreads();
    if (threadIdx.x == 0) {
        atomicAdd(&stats[2*m],   (double)((ls[0]+ls[1])+(ls[2]+ls[3])));
        atomicAdd(&stats[2*m+1], (double)((lq[0]+lq[1])+(lq[2]+lq[3])));
    }
}

// ---------- P2: codebook in LDS (reused x8), x via global_load_lds, counted vmcnt ----
#define NB  8   // b's per wave-iteration
#define BTI 8   // iterations per wave
__global__ __launch_bounds__(256)
void k_main(const float* __restrict__ xn, const float* __restrict__ Ck,
            const double* __restrict__ stats,
            float* __restrict__ hard, float* __restrict__ soft,
            float* __restrict__ part) {
    // LDS: [0, 8192) floats codebook (chunk-major); [8192, 10240) x-staging:
    //      per wave 2 buffers x 8 slices x 32 floats
    __shared__ float lds[10240];
    const int m = blockIdx.x;
    const int t = threadIdx.x, w = t >> 6, lane = t & 63;

    const double Ninv = 1.0 / ((double)BB * (double)KK);
    const double mu  = stats[2*m] * Ninv;
    const double var = stats[2*m+1] * Ninv - mu * mu;
    const float rstd = (float)(1.0 / sqrt(var + (double)BN_EPS));
    const float c1 = rstd * 1.4426950408889634f;   // softmax scale (shift cancels)

    // codebook -> LDS: thread t owns codeword k=t; chunk (j,i) holds
    // c[k=4l+j][4i..4i+3] at float idx ((j*8+i)*64 + l)*4
    {
        const f32x4* cg = (const f32x4*)(Ck + ((size_t)m * KK + t) * DD);
        const int j = t & 3, l = t >> 2;
        #pragma unroll
        for (int i = 0; i < 8; ++i)
            *(f32x4*)&lds[((j * 8 + i) * 64 + l) * 4] = cg[i];
    }
    __syncthreads();

    const int wbase = blockIdx.y * (4 * NB * BTI) + w * (NB * BTI);
    float* xlds = &lds[8192 + w * 512];            // 2 KB per wave

    auto stage = [&](int it) {                     // 1 KB via ONE global_load_lds
        const int b = wbase + it * NB + (lane >> 3);
        const float* gp = xn + (size_t)b * FEAT_DIM + m * DD + (lane & 7) * 4;
        __builtin_amdgcn_global_load_lds(
            (const __attribute__((address_space(1))) unsigned int*)gp,
            (__attribute__((address_space(3))) unsigned int*)&xlds[(it & 1) * 256],
            16, 0, 0);
    };

    auto FINISH = [&](float d0, float d1, float d2, float d3, int b) {
        const float p0 = exp2f(d0 * c1);
        const float p1 = exp2f(d1 * c1);
        const float p2 = exp2f(d2 * c1);
        const float p3 = exp2f(d3 * c1);

        const float mx = wave_dpp_max(fmaxf(fmaxf(d0, d1), fmaxf(d2, d3)));
        const unsigned long long m0 = __ballot(d0 == mx);
        const unsigned long long m1 = __ballot(d1 == mx);
        const unsigned long long m2 = __ballot(d2 == mx);
        const unsigned long long m3 = __ballot(d3 == mx);
        const int k0 = m0 ? 4*__builtin_ctzll(m0)+0 : 0x7fffffff;
        const int k1 = m1 ? 4*__builtin_ctzll(m1)+1 : 0x7fffffff;
        const int k2 = m2 ? 4*__builtin_ctzll(m2)+2 : 0x7fffffff;
        const int k3 = m3 ? 4*__builtin_ctzll(m3)+3 : 0x7fffffff;
        const int bi = min(min(k0, k1), min(k2, k3));   // first-index tie-break

        const float tot = wave_dpp_sum((p0 + p1) + (p2 + p3));
        const float inv = __builtin_amdgcn_rcpf(tot);

        f32x4 o = {p0*inv, p1*inv, p2*inv, p3*inv};
        __builtin_nontemporal_store(o, (f32x4*)(soft + ((size_t)b * MM + m) * KK) + lane);
        if (lane == 0) {
            hard[(size_t)b * MM + m] = (float)bi;          // store #2
            part[(size_t)m * BB + b] = 2.f - 2.f * mx;     // store #3
        }
        // exactly 3 vmem stores per FINISH -> 24 per iteration (vmcnt discipline)
    };

    stage(0);
    #pragma unroll 1
    for (int it = 0; it < BTI; ++it) {
        // retire the stage issued last iteration; leave its 24 younger stores in flight
        if (it == 0) asm volatile("s_waitcnt vmcnt(0)" ::: "memory");
        else         asm volatile("s_waitcnt vmcnt(24)" ::: "memory");
        __builtin_amdgcn_sched_barrier(0);
        if (it + 1 < BTI) stage(it + 1);
        __builtin_amdgcn_sched_barrier(0);

        const float* xb = &xlds[(it & 1) * 256];
        float acc[NB][4];
        #pragma unroll
        for (int s = 0; s < NB; ++s) {
            acc[s][0]=0.f; acc[s][1]=0.f; acc[s][2]=0.f; acc[s][3]=0.f;
        }
        #pragma unroll
        for (int i = 0; i < 8; ++i) {
            f32x4 cc0 = *(const f32x4*)&lds[((0 * 8 + i) * 64 + lane) * 4];
            f32x4 cc1 = *(const f32x4*)&lds[((1 * 8 + i) * 64 + lane) * 4];
            f32x4 cc2 = *(const f32x4*)&lds[((2 * 8 + i) * 64 + lane) * 4];
            f32x4 cc3 = *(const f32x4*)&lds[((3 * 8 + i) * 64 + lane) * 4];
            #pragma unroll
            for (int s = 0; s < NB; ++s) {
                const f32x4 xv = *(const f32x4*)&xb[s * 32 + i * 4];
                acc[s][0] = fmaf(xv[0], cc0[0], acc[s][0]);
                acc[s][0] = fmaf(xv[1], cc0[1], acc[s][0]);
                acc[s][0] = fmaf(xv[2], cc0[2], acc[s][0]);
                acc[s][0] = fmaf(xv[3], cc0[3], acc[s][0]);
                acc[s][1] = fmaf(xv[0], cc1[0], acc[s][1]);
                acc[s][1] = fmaf(xv[1], cc1[1], acc[s][1]);
                acc[s][1] = fmaf(xv[2], cc1[2], acc[s][1]);
                acc[s][1] = fmaf(xv[3], cc1[3], acc[s][1]);
                acc[s][2] = fmaf(xv[0], cc2[0], acc[s][2]);
                acc[s][2] = fmaf(xv[1], cc2[1], acc[s][2]);
                acc[s][2] = fmaf(xv[2], cc2[2], acc[s][2]);
                acc[s][2] = fmaf(xv[3], cc2[3], acc[s][2]);
                acc[s][3] = fmaf(xv[0], cc3[0], acc[s][3]);
                acc[s][3] = fmaf(xv[1], cc3[1], acc[s][3]);
                acc[s][3] = fmaf(xv[2], cc3[2], acc[s][3]);
                acc[s][3] = fmaf(xv[3], cc3[3], acc[s][3]);
            }
        }
        #pragma unroll
        for (int s = 0; s < NB; ++s)
            FINISH(acc[s][0], acc[s][1], acc[s][2], acc[s][3], wbase + it * NB + s);
    }
}

// ---------- P3: xhat[b][m] = Ck[m][hard[b][m]] — gather isolated here ----------
__global__ void k_xhat(const float* __restrict__ Ck, const float* __restrict__ hard,
                       float* __restrict__ xhat) {
    const int t = blockIdx.x * 256 + threadIdx.x;   // t < B*M*8
    const int i = t & 7, bm = t >> 3;
    const int m = bm & (MM - 1);
    const int k = (int)hard[bm];
    f32x4 cw = ((const f32x4*)(Ck + ((size_t)m * KK + k) * DD))[i];
    __builtin_nontemporal_store(cw, ((f32x4*)xhat) + (size_t)bm * 8 + i);
}

// ---------- P4: reg[b] = sum_m part[m][b] ----------
__global__ void k_regsum(const float* __restrict__ part, float* __restrict__ reg) {
    const int b = blockIdx.x * 256 + threadIdx.x;
    float a = 0.f;
    #pragma unroll
    for (int mm = 0; mm < MM; ++mm) a += part[(size_t)mm * BB + b];
    reg[b] = a;
}

extern "C" void kernel_launch(void* const* d_in, const int* in_sizes, int n_in,
                              void* d_out, int out_size, void* d_ws, size_t ws_size,
                              hipStream_t stream) {
    const float* x  = (const float*)d_in[0];
    const float* Ck = (const float*)d_in[1];

    float* out   = (float*)d_out;
    float* xhat  = out;                                   // B*FEAT
    float* hard  = xhat  + (size_t)BB * FEAT_DIM;         // B*M
    float* soft  = hard  + (size_t)BB * MM;               // B*M*K
    float* xnorm = soft  + (size_t)BB * MM * KK;          // B*FEAT
    float* reg   = xnorm + (size_t)BB * FEAT_DIM;         // B

    double* stats = (double*)d_ws;                        // M*2 doubles
    float* partb  = (float*)d_ws + 256;                   // M*B floats (1 MB) scratch
    float* Gbuf = soft;                                   // M*D*D floats (scratch, pre-k_main)
    float* Sbuf = soft + (size_t)MM * DD * DD;            // M*D floats

    k_norm<<<(BB * FEAT_DIM / 4) / 256, 256, 0, stream>>>(x, xnorm, stats);
    k_gram<<<dim3(MM, 8), 256, 0, stream>>>(Ck, Gbuf, Sbuf);
    k_stats2<<<dim3(MM, BB / 256), 256, 0, stream>>>(xnorm, Gbuf, Sbuf, stats);
    // per block: 4 waves x (NB*BTI=64) b's = 256 b's -> grid.y = 32
    k_main<<<dim3(MM, BB / 256), 256, 0, stream>>>(xnorm, Ck, stats, hard, soft, partb);
    k_xhat<<<(BB * MM * 8) / 256, 256, 0, stream>>>(Ck, hard, xhat);
    k_regsum<<<BB / 256, 256, 0, stream>>>(partb, reg);
}